// Round 8
// baseline (42.053 us; speedup 1.0000x reference)
//
#include <hip/hip_runtime.h>

#define B_ROWS 32768
#define C_COLS 1000
#define NF4 250                 // C_COLS / 4
#define MAIN_BLOCKS 2048
#define WAVES_TOTAL (MAIN_BLOCKS * 4)   // 8192; each wave does 4 strided rows
#define HIST_BLOCKS 16
#define BINS_PER_BLOCK 64       // 16 * 64 = 1024 >= 1000

// --- histogram: each of 16 blocks histograms ALL labels in LDS, then
//     writes only its owned 64-bin slice (round-7 proven). ---
__global__ __launch_bounds__(256) void bsl_hist(const int* __restrict__ target,
                                                float* __restrict__ freq) {
    __shared__ unsigned int lh[1024];
    const int tid = threadIdx.x;
    #pragma unroll
    for (int i = tid; i < 1024; i += 256) lh[i] = 0u;
    __syncthreads();
    const int4* t4 = reinterpret_cast<const int4*>(target);
    #pragma unroll 8
    for (int k = 0; k < 32; ++k) {
        int4 v = t4[tid + k * 256];
        atomicAdd(&lh[v.x], 1u);
        atomicAdd(&lh[v.y], 1u);
        atomicAdd(&lh[v.z], 1u);
        atomicAdd(&lh[v.w], 1u);
    }
    __syncthreads();
    if (tid < BINS_PER_BLOCK) {
        const int bin = blockIdx.x * BINS_PER_BLOCK + tid;
        freq[bin] = (float)lh[bin];
    }
}

// --- main: round-2 math, explicitly software-pipelined across the 4 rows.
//     Two named register buffers (static indexing), loads for row r+1 issued
//     before row r is consumed. ---
__global__ __launch_bounds__(256, 8) void bsl_main(const float* __restrict__ pred,
                                                   const int* __restrict__ target,
                                                   const float* __restrict__ freq,
                                                   float* __restrict__ partials) {
    __shared__ float sfreq[C_COLS];
    __shared__ float swave[4];
    const int tid = threadIdx.x;
    const int lane = tid & 63;
    const int wib = tid >> 6;

    for (int i = tid; i < C_COLS; i += 256) sfreq[i] = freq[i];
    __syncthreads();
    const float4* sf4 = reinterpret_cast<const float4*>(sfreq);

    const int gwid = blockIdx.x * 4 + wib;

    // hoist all 4 target loads (independent of pred loads)
    const int t0 = target[gwid];
    const int t1 = target[gwid + WAVES_TOTAL];
    const int t2 = target[gwid + 2 * WAVES_TOTAL];
    const int t3 = target[gwid + 3 * WAVES_TOTAL];

    float4 va[4], vb[4];
    float local = 0.0f;

#define LOADV(V, ROW)                                                          \
    {                                                                          \
        const float4* pp =                                                     \
            reinterpret_cast<const float4*>(pred + (size_t)(ROW) * C_COLS);   \
        _Pragma("unroll")                                                      \
        for (int k = 0; k < 4; ++k) {                                          \
            const int j = k * 64 + lane;                                       \
            if (j < NF4) V[k] = pp[j];                                         \
        }                                                                      \
    }

#define COMPUTEV(V, T)                                                         \
    {                                                                          \
        const int t4i = (T) >> 2, tm = (T) & 3;                                \
        float partial = 0.0f, pt = 0.0f;                                       \
        _Pragma("unroll")                                                      \
        for (int k = 0; k < 4; ++k) {                                          \
            const int j = k * 64 + lane;                                       \
            if (j < NF4) {                                                     \
                const float4 f = sf4[j];                                       \
                const float4 a = V[k];                                         \
                partial += __expf(a.x) * f.x + __expf(a.y) * f.y               \
                         + __expf(a.z) * f.z + __expf(a.w) * f.w;              \
                if (j == t4i)                                                  \
                    pt = (tm & 1) ? ((tm & 2) ? a.w : a.y)                     \
                                  : ((tm & 2) ? a.z : a.x);                    \
            }                                                                  \
        }                                                                      \
        _Pragma("unroll")                                                      \
        for (int off = 32; off > 0; off >>= 1)                                 \
            partial += __shfl_xor(partial, off, 64);                           \
        const float ptb = __shfl(pt, t4i & 63, 64);                            \
        local += logf(partial) - ptb - logf(sfreq[T]);                         \
    }

    // software pipeline: loads for the next row are in flight during the
    // current row's exp + butterfly + logf tail
    LOADV(va, gwid);
    LOADV(vb, gwid + WAVES_TOTAL);
    COMPUTEV(va, t0);
    LOADV(va, gwid + 2 * WAVES_TOTAL);
    COMPUTEV(vb, t1);
    LOADV(vb, gwid + 3 * WAVES_TOTAL);
    COMPUTEV(va, t2);
    COMPUTEV(vb, t3);

#undef LOADV
#undef COMPUTEV

    // `local` is identical across the wave; block-reduce the 4 wave values
    if (lane == 0) swave[wib] = local;
    __syncthreads();
    if (tid == 0)
        partials[blockIdx.x] = swave[0] + swave[1] + swave[2] + swave[3];
}

__global__ __launch_bounds__(256) void bsl_finalize(const float* __restrict__ partials,
                                                    float* __restrict__ out) {
    const int tid = threadIdx.x;
    float s = 0.0f;
    for (int i = tid; i < MAIN_BLOCKS; i += 256) s += partials[i];
    #pragma unroll
    for (int off = 32; off > 0; off >>= 1) s += __shfl_xor(s, off, 64);
    __shared__ float sw[4];
    if ((tid & 63) == 0) sw[tid >> 6] = s;
    __syncthreads();
    if (tid == 0) out[0] = (sw[0] + sw[1] + sw[2] + sw[3]) / (float)B_ROWS;
}

extern "C" void kernel_launch(void* const* d_in, const int* in_sizes, int n_in,
                              void* d_out, int out_size, void* d_ws, size_t ws_size,
                              hipStream_t stream) {
    const float* pred = (const float*)d_in[0];
    const int* target = (const int*)d_in[1];

    float* freq     = (float*)d_ws;          // [1024]
    float* partials = freq + 1024;           // [MAIN_BLOCKS]

    bsl_hist<<<HIST_BLOCKS, 256, 0, stream>>>(target, freq);
    bsl_main<<<MAIN_BLOCKS, 256, 0, stream>>>(pred, target, freq, partials);
    bsl_finalize<<<1, 256, 0, stream>>>(partials, (float*)d_out);
}